// Round 7
// baseline (7992.657 us; speedup 1.0000x reference)
//
#include <hip/hip_runtime.h>
#include <hip/hip_fp16.h>

// ============================================================================
// ChunkParallelGRU on MI355X (gfx950) — R9: overlap staging with MFMA
//
// Ledger: R5 = best (5.40ms seq, 10.55us/step). R4/R6/R7 restructures failed
// (hang/VGPR catastrophe); R8 protocol polish regressed (+1.5us/step from SA
// barrier + coop staging + poll4). R9 returns to R5 byte-for-byte except:
//  1. S0 barrier removed. Waves 0/1 stage their 16-kk half of als, drain
//     lgkmcnt, bump an LDS token, then MFMA their OWN half immediately and
//     spin the other wave's token mid-chain -> staging overlaps MFMA.
//     Waves 2/3 need no tokens: S1 barrier semantics guarantee als complete
//     (waves 0/1 reach S1 only after consuming both halves).
//     Cross-step als safety unchanged: own wave2's h-publish gates own
//     wave0/1's next ch-poll (self-gating counter, as in R5).
//  2. 2-acc ILP split in phase B only (waves 0/1 are register-light);
//     waves 2/3 keep R5's exact single-acc code (R8's 2-acc there is the
//     suspected register-pressure regression).
//  3. xv4 (HBM, cold) issued before staging loads to hide its latency.
// Gates, layouts, workspace map: byte-identical to R5.
// ============================================================================

typedef _Float16 half8 __attribute__((ext_vector_type(8)));
typedef _Float16 half4v __attribute__((ext_vector_type(4)));
typedef float    floatx4 __attribute__((ext_vector_type(4)));

#define T_STEPS 512

#define AL(p)    __hip_atomic_load((p), __ATOMIC_RELAXED, __HIP_MEMORY_SCOPE_AGENT)
#define AS(p, v) __hip_atomic_store((p), (v), __ATOMIC_RELAXED, __HIP_MEMORY_SCOPE_AGENT)
#define AADD(p)  __hip_atomic_fetch_add((p), 1u, __ATOMIC_RELAXED, __HIP_MEMORY_SCOPE_AGENT)

union U16 { unsigned long long u[2]; half8 h; };

// poll ONE uniform counter word until it reaches target (monotone)
__device__ __forceinline__ void poll_cnt(const unsigned* c, unsigned target) {
    unsigned v = AL(c);
    while (v < target) {
        if (target - v > 8u) __builtin_amdgcn_s_sleep(2);
        v = AL(c);
    }
    asm volatile("" ::: "memory");  // keep later mem ops after the spin
}

// spin on an LDS token (workgroup-local; producer drained lgkmcnt before bump)
__device__ __forceinline__ void spin_tok(const unsigned* tok, unsigned target) {
    while (__hip_atomic_load(tok, __ATOMIC_RELAXED, __HIP_MEMORY_SCOPE_WORKGROUP) < target)
        ;
    asm volatile("" ::: "memory");
    __builtin_amdgcn_sched_barrier(0);  // rule #18: fence scheduler too
}

// ---------------------------------------------------------------------------
// 1) transpose+convert x-part of Wz/Wr/Wh -> wxT[n=3072][k=1024] f16
// ---------------------------------------------------------------------------
__global__ void pack_wxT(const float* __restrict__ Wz, const float* __restrict__ Wr,
                         const float* __restrict__ Wh, _Float16* __restrict__ wxT) {
    __shared__ float tile[64][65];
    const int k0 = blockIdx.x * 64;
    const int c0 = blockIdx.y * 64;
    const int gate = blockIdx.z;
    const float* W = (gate == 0) ? Wz : ((gate == 1) ? Wr : Wh);
    const int tid = threadIdx.x;
    const int tc = tid & 63;
    const int tr = tid >> 6;
#pragma unroll
    for (int rr = 0; rr < 16; ++rr) {
        int kr = rr * 4 + tr;
        tile[kr][tc] = W[(size_t)(k0 + kr) * 1024 + c0 + tc];
    }
    __syncthreads();
#pragma unroll
    for (int rr = 0; rr < 16; ++rr) {
        int nr = rr * 4 + tr;
        wxT[(size_t)(gate * 1024 + c0 + nr) * 1024 + k0 + tc] = (_Float16)tile[tc][nr];
    }
}

// ---------------------------------------------------------------------------
// 2) recurrent weights -> per-wg MFMA B-fragment images
//    wpack[((j*4+mat)*32+kk)*64+lane][e] = W_mat[k=kk*32+(lane>>4)*8+e][n=j*16+(lane&15)]
// ---------------------------------------------------------------------------
__global__ void pack_wrec(const float* __restrict__ Wz, const float* __restrict__ Wr,
                          const float* __restrict__ Wh, const float* __restrict__ Wp,
                          _Float16* __restrict__ wpack) {
    int idx = blockIdx.x * 256 + threadIdx.x;
    int mat = (idx >> 11) & 3;
    int kk = (idx >> 6) & 31;
    int lane = idx & 63;
    int j = idx >> 13;
    int n = j * 16 + (lane & 15);
    int kb = kk * 32 + (lane >> 4) * 8;
    const float* W = (mat == 0) ? Wz : ((mat == 1) ? Wr : ((mat == 2) ? Wh : Wp));
    size_t rowoff = (mat < 3) ? 1024 : 0;
#pragma unroll
    for (int e = 0; e < 8; ++e)
        wpack[(size_t)idx * 8 + e] = (_Float16)W[(rowoff + kb + e) * 1024 + n];
}

// ---------------------------------------------------------------------------
// 3) h0 -> A-fragment image (event 0); zero sync counters
// ---------------------------------------------------------------------------
__global__ void init_misc(const float* __restrict__ h0, _Float16* __restrict__ hfrag,
                          unsigned* __restrict__ flags) {
    int idx = blockIdx.x * 256 + threadIdx.x;  // 0..8191
    int g = idx >> 11;
    int kk = (idx >> 6) & 31;
    int lane = idx & 63;
    int b = lane & 15;
    int kb = kk * 32 + (lane >> 4) * 8;
#pragma unroll
    for (int e = 0; e < 8; ++e)
        hfrag[(size_t)g * 16384 + (size_t)(kk * 64 + lane) * 8 + e] =
            (_Float16)h0[(size_t)(g * 16 + b) * 1024 + kb + e];
    if (blockIdx.x == 0) {
        flags[threadIdx.x] = 0;
        flags[threadIdx.x + 256] = 0;
        flags[threadIdx.x + 512] = 0;
    }
}

// ---------------------------------------------------------------------------
// 4) Xtmp = x @ wxT^T + bias, stored as [(g*64+j)*3+mat][t][c*16+b] f16
// ---------------------------------------------------------------------------
__global__ __launch_bounds__(256) void xproj_gemm(
    const float* __restrict__ x, const _Float16* __restrict__ wxT,
    const float* __restrict__ bz, const float* __restrict__ br,
    const float* __restrict__ bh, _Float16* __restrict__ Xtmp) {
    __shared__ _Float16 Als[128][40];
    __shared__ _Float16 Bls[128][40];
    const int tid = threadIdx.x;
    const int n0 = blockIdx.x * 128;
    const int m0 = blockIdx.y * 128;
    const int lane = tid & 63;
    const int wave = tid >> 6;
    const int lm = lane & 15, lq = lane >> 4;
    const int wm = (wave >> 1) * 64, wn = (wave & 1) * 64;
    const int srow = tid >> 1;
    const int shalf = (tid & 1) * 16;

    floatx4 acc[4][4];
#pragma unroll
    for (int mi = 0; mi < 4; ++mi)
#pragma unroll
        for (int ni = 0; ni < 4; ++ni) acc[mi][ni] = (floatx4){0.f, 0.f, 0.f, 0.f};

    for (int k0 = 0; k0 < 1024; k0 += 32) {
        {
            const float* src = x + (size_t)(m0 + srow) * 1024 + k0 + shalf;
            float4 p0 = ((const float4*)src)[0];
            float4 p1 = ((const float4*)src)[1];
            float4 p2 = ((const float4*)src)[2];
            float4 p3 = ((const float4*)src)[3];
            half8 h0v = {(_Float16)p0.x, (_Float16)p0.y, (_Float16)p0.z, (_Float16)p0.w,
                         (_Float16)p1.x, (_Float16)p1.y, (_Float16)p1.z, (_Float16)p1.w};
            half8 h1v = {(_Float16)p2.x, (_Float16)p2.y, (_Float16)p2.z, (_Float16)p2.w,
                         (_Float16)p3.x, (_Float16)p3.y, (_Float16)p3.z, (_Float16)p3.w};
            *(half8*)&Als[srow][shalf] = h0v;
            *(half8*)&Als[srow][shalf + 8] = h1v;
            const _Float16* bsrc = wxT + (size_t)(n0 + srow) * 1024 + k0 + shalf;
            *(half8*)&Bls[srow][shalf] = ((const half8*)bsrc)[0];
            *(half8*)&Bls[srow][shalf + 8] = ((const half8*)bsrc)[1];
        }
        __syncthreads();
        half8 af[4], bf[4];
#pragma unroll
        for (int mi = 0; mi < 4; ++mi) af[mi] = *(const half8*)&Als[wm + mi * 16 + lm][lq * 8];
#pragma unroll
        for (int ni = 0; ni < 4; ++ni) bf[ni] = *(const half8*)&Bls[wn + ni * 16 + lm][lq * 8];
#pragma unroll
        for (int mi = 0; mi < 4; ++mi)
#pragma unroll
            for (int ni = 0; ni < 4; ++ni)
                acc[mi][ni] = __builtin_amdgcn_mfma_f32_16x16x32_f16(af[mi], bf[ni], acc[mi][ni], 0, 0, 0);
        __syncthreads();
    }
    // epilogue -> layout: idx = (((g*64+j)*3+mat)*512 + t)*256 + c*16 + b
#pragma unroll
    for (int mi = 0; mi < 4; ++mi) {
#pragma unroll
        for (int i = 0; i < 4; ++i) {
            int row = m0 + wm + mi * 16 + lq * 4 + i;  // (g*16+b)*512 + t
            int t = row & 511;
            int bglob = row >> 9;
            int g = bglob >> 4, b = bglob & 15;
#pragma unroll
            for (int ni = 0; ni < 4; ++ni) {
                int col = n0 + wn + ni * 16 + lm;  // mat*1024 + j*16 + c
                int mat = col >> 10;
                int jc = col - mat * 1024;
                int jj = jc >> 4, c = jc & 15;
                float bias = (mat == 0) ? bz[jc] : ((mat == 1) ? br[jc] : bh[jc]);
                size_t idx = ((((size_t)(g * 64 + jj) * 3 + mat) * 512 + t) << 8) + c * 16 + b;
                Xtmp[idx] = (_Float16)(acc[mi][ni][i] + bias);
            }
        }
    }
}

// ---------------------------------------------------------------------------
// 5) persistent sequential kernel — R5 shape + token-pipelined staging
//    counters: ch threshold 64t, cr 64(t+1), cn 64((t+1)>>2)
// ---------------------------------------------------------------------------
__global__ __launch_bounds__(256, 1) void gru_seq_kernel(
    const _Float16* __restrict__ Xtmp, const _Float16* __restrict__ wpack,
    const float* __restrict__ h0,
    _Float16* __restrict__ hfrag,   // [2][4][16384]
    _Float16* __restrict__ rfrag,   // [4][16384]
    _Float16* __restrict__ hnfrag,  // [4][16384]
    unsigned* flags_h, unsigned* flags_r, unsigned* flags_n,
    const float* __restrict__ bp, float* __restrict__ out) {
    const int wg = blockIdx.x;
    const int g = wg & 3;
    const int j = wg >> 2;
    const int tid = threadIdx.x;
    const int wave = tid >> 6;
    const int lane = tid & 63;
    const int lm = lane & 15;
    const int lq = lane >> 4;

    __shared__ __align__(16) _Float16 als[32 * 64 * 8];  // 32KB staged h A-frags
    __shared__ float zbuf[256];
    __shared__ float pbuf[256];
    __shared__ _Float16 rbuf[256];
    __shared__ _Float16 hbuf[256];
    __shared__ _Float16 nbuf[256];
    __shared__ unsigned tok0, tok1;   // staging half-tokens (monotone t+1)

    if (tid == 0) { tok0 = 0u; tok1 = 0u; }
    __syncthreads();

    // persistent B-fragments: wave w holds matrix w (z,r,hc,Wp), 128 VGPR
    half8 W[32];
    {
        const half8* wp = (const half8*)wpack + (size_t)((j * 4 + wave) * 32) * 64 + lane;
#pragma unroll
        for (int kk = 0; kk < 32; ++kk) W[kk] = wp[kk * 64];
    }
    const float bpl = bp[j * 16 + lm];

    // one counter per (group, phase), 256B apart (separate cache lines)
    unsigned* ch = flags_h + g * 64;
    unsigned* cr = flags_r + g * 64;
    unsigned* cn = flags_n + g * 64;

    // transpose-store lane roles: one 8B chunk per lane covers the wg's
    // 16x16 output slice in A-frag order
    const int kkd = j >> 1;
    const int s_ = lane >> 5;
    const int b_ = (lane >> 1) & 15;
    const int hp_ = lane & 1;
    const size_t fidx = (size_t)((kkd * 64 + (2 * (j & 1) + s_) * 16 + b_) * 2 + hp_);
    const int ldsrd = b_ * 16 + s_ * 8 + hp_ * 4;  // halves offset in 16x16 buf

    // wave2 persistent h registers (own slice: b=lq*4+i, col=j*16+lm)
    float hreg[4];
    if (wave == 2) {
#pragma unroll
        for (int i = 0; i < 4; ++i)
            hreg[i] = h0[(size_t)(g * 16 + lq * 4 + i) * 1024 + j * 16 + lm];
    }

    unsigned long long* als8 = (unsigned long long*)als;

    for (int t = 0; t < T_STEPS; ++t) {
        const bool boundary = ((t & 3) == 3) && (t != T_STEPS - 1);

        // ---- phase A+B fused (waves 0,1): poll, stage own half, token,
        //      MFMA own half, spin other token, MFMA other half ----
        if (wave < 2) {
            poll_cnt(ch, 64u * (unsigned)t);
            // issue cold Xtmp load early (HBM latency hides under staging)
            half4v xv4 = *(const half4v*)(Xtmp +
                ((((size_t)(g * 64 + j) * 3 + wave) * 512 + t) << 8) + lm * 16 + lq * 4);
            const unsigned long long* hp8 =
                (const unsigned long long*)(hfrag + (size_t)((t & 1) * 4 + g) * 16384);
            const int ownb = wave * 16;   // wave0: kk 0..15, wave1: kk 16..31
            const int othb = 16 - ownb;
            {
                unsigned long long tmp[32];
#pragma unroll
                for (int q = 0; q < 16; ++q) {
                    int kk = ownb + q;
                    tmp[2 * q]     = AL(hp8 + (size_t)(kk * 64 + lane) * 2);
                    tmp[2 * q + 1] = AL(hp8 + (size_t)(kk * 64 + lane) * 2 + 1);
                }
#pragma unroll
                for (int q = 0; q < 16; ++q) {
                    int kk = ownb + q;
                    als8[(kk * 64 + lane) * 2] = tmp[2 * q];
                    als8[(kk * 64 + lane) * 2 + 1] = tmp[2 * q + 1];
                }
            }
            asm volatile("s_waitcnt lgkmcnt(0)" ::: "memory");  // drain ds_writes
            if (lane == 0)
                __hip_atomic_store(wave == 0 ? &tok0 : &tok1, (unsigned)(t + 1),
                                   __ATOMIC_RELAXED, __HIP_MEMORY_SCOPE_WORKGROUP);
            // MFMA own half (2-acc ILP)
            floatx4 a0 = {0.f, 0.f, 0.f, 0.f}, a1 = {0.f, 0.f, 0.f, 0.f};
#pragma unroll
            for (int q = 0; q < 16; q += 2) {
                int kk = ownb + q;
                half8 av0 = *(const half8*)&als[(kk * 64 + lane) * 8];
                half8 av1 = *(const half8*)&als[((kk + 1) * 64 + lane) * 8];
                a0 = __builtin_amdgcn_mfma_f32_16x16x32_f16(av0, W[kk], a0, 0, 0, 0);
                a1 = __builtin_amdgcn_mfma_f32_16x16x32_f16(av1, W[kk + 1], a1, 0, 0, 0);
            }
            // other half (wait for sibling wave's staging)
            spin_tok(wave == 0 ? &tok1 : &tok0, (unsigned)(t + 1));
#pragma unroll
            for (int q = 0; q < 16; q += 2) {
                int kk = othb + q;
                half8 av0 = *(const half8*)&als[(kk * 64 + lane) * 8];
                half8 av1 = *(const half8*)&als[((kk + 1) * 64 + lane) * 8];
                a0 = __builtin_amdgcn_mfma_f32_16x16x32_f16(av0, W[kk], a0, 0, 0, 0);
                a1 = __builtin_amdgcn_mfma_f32_16x16x32_f16(av1, W[kk + 1], a1, 0, 0, 0);
            }
            floatx4 acc = a0 + a1;
            if (wave == 0) {
#pragma unroll
                for (int i = 0; i < 4; ++i)
                    zbuf[lane * 4 + i] = 1.f / (1.f + __expf(-(acc[i] + (float)xv4[i])));
            } else {
#pragma unroll
                for (int i = 0; i < 4; ++i)
                    rbuf[(lq * 4 + i) * 16 + lm] =
                        (_Float16)(1.f / (1.f + __expf(-(acc[i] + (float)xv4[i]))));
                asm volatile("s_waitcnt lgkmcnt(0)" ::: "memory");
                unsigned long long rv8 = *(const unsigned long long*)&rbuf[ldsrd];
                AS((unsigned long long*)(rfrag + (size_t)g * 16384) + fidx, rv8);
                asm volatile("s_waitcnt vmcnt(0)" ::: "memory");  // release
                if (lane == 0) AADD(cr);
            }
        }
        __syncthreads();  // S1: zbuf + als complete (waves 0/1 consumed both halves)

        // ---- phase C: candidate + blend (wave 2) / projection (wave 3) ----
        if (wave == 2) {
            half4v xv4 = *(const half4v*)(Xtmp +
                ((((size_t)(g * 64 + j) * 3 + 2) * 512 + t) << 8) + lm * 16 + lq * 4);
            poll_cnt(cr, 64u * (unsigned)(t + 1));
            const unsigned long long* rr8 = (const unsigned long long*)(rfrag + (size_t)g * 16384);
            // batch ALL r-fragment loads before the MFMA loop (one MALL latency)
            unsigned long long rtmp[64];
#pragma unroll
            for (int kk = 0; kk < 32; ++kk) {
                rtmp[2 * kk]     = AL(rr8 + (size_t)(kk * 64 + lane) * 2);
                rtmp[2 * kk + 1] = AL(rr8 + (size_t)(kk * 64 + lane) * 2 + 1);
            }
            floatx4 acc = {0.f, 0.f, 0.f, 0.f};
#pragma unroll
            for (int kk = 0; kk < 32; ++kk) {
                half8 av = *(const half8*)&als[(kk * 64 + lane) * 8];
                U16 rc;
                rc.u[0] = rtmp[2 * kk];
                rc.u[1] = rtmp[2 * kk + 1];
                half8 prod = av * rc.h;
                acc = __builtin_amdgcn_mfma_f32_16x16x32_f16(prod, W[kk], acc, 0, 0, 0);
            }
            const bool post_b = (t > 0) && ((t & 3) == 0);
            float hn_[4];
#pragma unroll
            for (int i = 0; i < 4; ++i) {
                float hp = post_b ? pbuf[(lq * 4 + i) * 16 + lm] : hreg[i];
                float z = zbuf[lane * 4 + i];
                float hc = tanhf(acc[i] + (float)xv4[i]);
                float hn = (1.f - z) * hp + z * hc;
                hn_[i] = hn;
                hreg[i] = hn;
                hbuf[(lq * 4 + i) * 16 + lm] = (_Float16)hn;
            }
            asm volatile("s_waitcnt lgkmcnt(0)" ::: "memory");
            unsigned long long hv8 = *(const unsigned long long*)&hbuf[ldsrd];
            unsigned long long* dst8 = (unsigned long long*)(boundary
                ? (hnfrag + (size_t)g * 16384)
                : (hfrag + (size_t)(((t + 1) & 1) * 4 + g) * 16384));
            AS(dst8 + fidx, hv8);
            asm volatile("s_waitcnt vmcnt(0)" ::: "memory");  // release
            if (t < T_STEPS - 1 && lane == 0) {
                if (boundary) AADD(cn);
                else          AADD(ch);
            }
            // out[] stores AFTER the publish (off the release path)
#pragma unroll
            for (int i = 0; i < 4; ++i)
                __builtin_nontemporal_store(hn_[i],
                    &out[(size_t)((g * 16 + lq * 4 + i) * 512 + t) * 1024 + j * 16 + lm]);
        } else if (wave == 3 && boundary) {
            poll_cnt(cn, 64u * (unsigned)((t + 1) >> 2));
            const unsigned long long* nn8 = (const unsigned long long*)(hnfrag + (size_t)g * 16384);
            unsigned long long ntmp[64];
#pragma unroll
            for (int kk = 0; kk < 32; ++kk) {
                ntmp[2 * kk]     = AL(nn8 + (size_t)(kk * 64 + lane) * 2);
                ntmp[2 * kk + 1] = AL(nn8 + (size_t)(kk * 64 + lane) * 2 + 1);
            }
            floatx4 acc = {0.f, 0.f, 0.f, 0.f};
#pragma unroll
            for (int kk = 0; kk < 32; ++kk) {
                U16 nc;
                nc.u[0] = ntmp[2 * kk];
                nc.u[1] = ntmp[2 * kk + 1];
                acc = __builtin_amdgcn_mfma_f32_16x16x32_f16(nc.h, W[kk], acc, 0, 0, 0);
            }
#pragma unroll
            for (int i = 0; i < 4; ++i) {
                float hv = tanhf(acc[i] + bpl);
                pbuf[(lq * 4 + i) * 16 + lm] = hv;            // handoff to wave2 (t+1)
                nbuf[(lq * 4 + i) * 16 + lm] = (_Float16)hv;
            }
            asm volatile("s_waitcnt lgkmcnt(0)" ::: "memory");
            unsigned long long nv8 = *(const unsigned long long*)&nbuf[ldsrd];
            AS((unsigned long long*)(hfrag + (size_t)(((t + 1) & 1) * 4 + g) * 16384) + fidx, nv8);
            asm volatile("s_waitcnt vmcnt(0)" ::: "memory");  // release
            if (lane == 0) AADD(ch);
        }
    }
}

// ---------------------------------------------------------------------------
// host launcher
// ---------------------------------------------------------------------------
extern "C" void kernel_launch(void* const* d_in, const int* in_sizes, int n_in,
                              void* d_out, int out_size, void* d_ws, size_t ws_size,
                              hipStream_t stream) {
    (void)in_sizes; (void)n_in; (void)out_size; (void)ws_size;
    const float* x  = (const float*)d_in[0];
    const float* h0 = (const float*)d_in[1];
    const float* Wz = (const float*)d_in[2];
    const float* bz = (const float*)d_in[3];
    const float* Wr = (const float*)d_in[4];
    const float* br = (const float*)d_in[5];
    const float* Wh = (const float*)d_in[6];
    const float* bh = (const float*)d_in[7];
    const float* Wp = (const float*)d_in[8];
    const float* bp = (const float*)d_in[9];
    float* out = (float*)d_out;

    char* ws = (char*)d_ws;
    _Float16* wxT    = (_Float16*)(ws);                // 6,291,456 B
    _Float16* wpack  = (_Float16*)(ws + 6291456);      // 8,388,608 B
    _Float16* Xtmp   = (_Float16*)(ws + 14680064);     // 201,326,592 B
    _Float16* hfrag  = (_Float16*)(ws + 216006656);    // 262,144 B  [2][4][16384]
    _Float16* rfrag  = (_Float16*)(ws + 216268800);    // 131,072 B  [4][16384]
    _Float16* hnfrag = (_Float16*)(ws + 216399872);    // 131,072 B  [4][16384]
    unsigned* flags  = (unsigned*)(ws + 216530944);    // 3,072 B (counters)
    unsigned* flags_h = flags;
    unsigned* flags_r = flags + 256;
    unsigned* flags_n = flags + 512;

    pack_wxT<<<dim3(16, 16, 3), 256, 0, stream>>>(Wz, Wr, Wh, wxT);
    pack_wrec<<<2048, 256, 0, stream>>>(Wz, Wr, Wh, Wp, wpack);
    init_misc<<<32, 256, 0, stream>>>(h0, hfrag, flags);
    xproj_gemm<<<dim3(24, 256), 256, 0, stream>>>(x, wxT, bz, br, bh, Xtmp);
    gru_seq_kernel<<<256, 256, 0, stream>>>(Xtmp, wpack, h0, hfrag, rfrag, hnfrag,
                                            flags_h, flags_r, flags_n, bp, out);
}

// Round 8
// 5932.255 us; speedup vs baseline: 1.3473x; 1.3473x over previous
//
#include <hip/hip_runtime.h>
#include <hip/hip_fp16.h>

// ============================================================================
// ChunkParallelGRU on MI355X (gfx950) — R10: R5 + two attributable micro-fixes
//
// Ledger: R5 = best (5.40ms seq, 10.55us/step, 6.44ms total). R4 hang,
// R6/R7 VGPR catastrophe, R8/R9 sync-topology polish regressed. Rule learned:
// R5's sync structure is a local optimum; only local, attributable changes.
//
// R10 = R5 byte-for-byte EXCEPT:
//  1. waves 0/1 issue their xv4 (cold HBM, ~900ns) at step start BEFORE the
//     ch-poll, not after S0 right before the sigmoid. In R5 the z/r MFMA
//     chain (~0.2-0.6us) is too short to cover the HBM latency, so the
//     r-publish — which gates wave2 of all 64 wgs — eats an avoidable
//     ~0.3-0.7us stall every step. (Wave2's xv4 was already early in R5.)
//  2. 2-accumulator ILP in the three 32-MFMA chains (dep latency->throughput;
//     proven spill-free by R8's counters: VGPR 256, FETCH normal).
// Gates, staging, batched loads, layouts, workspace map: identical to R5.
// ============================================================================

typedef _Float16 half8 __attribute__((ext_vector_type(8)));
typedef _Float16 half4v __attribute__((ext_vector_type(4)));
typedef float    floatx4 __attribute__((ext_vector_type(4)));

#define T_STEPS 512

#define AL(p)    __hip_atomic_load((p), __ATOMIC_RELAXED, __HIP_MEMORY_SCOPE_AGENT)
#define AS(p, v) __hip_atomic_store((p), (v), __ATOMIC_RELAXED, __HIP_MEMORY_SCOPE_AGENT)
#define AADD(p)  __hip_atomic_fetch_add((p), 1u, __ATOMIC_RELAXED, __HIP_MEMORY_SCOPE_AGENT)

union U16 { unsigned long long u[2]; half8 h; };

// poll ONE uniform counter word until it reaches target (monotone)
__device__ __forceinline__ void poll_cnt(const unsigned* c, unsigned target) {
    unsigned v = AL(c);
    while (v < target) {
        if (target - v > 8u) __builtin_amdgcn_s_sleep(2);
        v = AL(c);
    }
    asm volatile("" ::: "memory");  // keep later mem ops after the spin
}

// ---------------------------------------------------------------------------
// 1) transpose+convert x-part of Wz/Wr/Wh -> wxT[n=3072][k=1024] f16
// ---------------------------------------------------------------------------
__global__ void pack_wxT(const float* __restrict__ Wz, const float* __restrict__ Wr,
                         const float* __restrict__ Wh, _Float16* __restrict__ wxT) {
    __shared__ float tile[64][65];
    const int k0 = blockIdx.x * 64;
    const int c0 = blockIdx.y * 64;
    const int gate = blockIdx.z;
    const float* W = (gate == 0) ? Wz : ((gate == 1) ? Wr : Wh);
    const int tid = threadIdx.x;
    const int tc = tid & 63;
    const int tr = tid >> 6;
#pragma unroll
    for (int rr = 0; rr < 16; ++rr) {
        int kr = rr * 4 + tr;
        tile[kr][tc] = W[(size_t)(k0 + kr) * 1024 + c0 + tc];
    }
    __syncthreads();
#pragma unroll
    for (int rr = 0; rr < 16; ++rr) {
        int nr = rr * 4 + tr;
        wxT[(size_t)(gate * 1024 + c0 + nr) * 1024 + k0 + tc] = (_Float16)tile[tc][nr];
    }
}

// ---------------------------------------------------------------------------
// 2) recurrent weights -> per-wg MFMA B-fragment images
//    wpack[((j*4+mat)*32+kk)*64+lane][e] = W_mat[k=kk*32+(lane>>4)*8+e][n=j*16+(lane&15)]
// ---------------------------------------------------------------------------
__global__ void pack_wrec(const float* __restrict__ Wz, const float* __restrict__ Wr,
                          const float* __restrict__ Wh, const float* __restrict__ Wp,
                          _Float16* __restrict__ wpack) {
    int idx = blockIdx.x * 256 + threadIdx.x;
    int mat = (idx >> 11) & 3;
    int kk = (idx >> 6) & 31;
    int lane = idx & 63;
    int j = idx >> 13;
    int n = j * 16 + (lane & 15);
    int kb = kk * 32 + (lane >> 4) * 8;
    const float* W = (mat == 0) ? Wz : ((mat == 1) ? Wr : ((mat == 2) ? Wh : Wp));
    size_t rowoff = (mat < 3) ? 1024 : 0;
#pragma unroll
    for (int e = 0; e < 8; ++e)
        wpack[(size_t)idx * 8 + e] = (_Float16)W[(rowoff + kb + e) * 1024 + n];
}

// ---------------------------------------------------------------------------
// 3) h0 -> A-fragment image (event 0); zero sync counters
// ---------------------------------------------------------------------------
__global__ void init_misc(const float* __restrict__ h0, _Float16* __restrict__ hfrag,
                          unsigned* __restrict__ flags) {
    int idx = blockIdx.x * 256 + threadIdx.x;  // 0..8191
    int g = idx >> 11;
    int kk = (idx >> 6) & 31;
    int lane = idx & 63;
    int b = lane & 15;
    int kb = kk * 32 + (lane >> 4) * 8;
#pragma unroll
    for (int e = 0; e < 8; ++e)
        hfrag[(size_t)g * 16384 + (size_t)(kk * 64 + lane) * 8 + e] =
            (_Float16)h0[(size_t)(g * 16 + b) * 1024 + kb + e];
    if (blockIdx.x == 0) {
        flags[threadIdx.x] = 0;
        flags[threadIdx.x + 256] = 0;
        flags[threadIdx.x + 512] = 0;
    }
}

// ---------------------------------------------------------------------------
// 4) Xtmp = x @ wxT^T + bias, stored as [(g*64+j)*3+mat][t][c*16+b] f16
// ---------------------------------------------------------------------------
__global__ __launch_bounds__(256) void xproj_gemm(
    const float* __restrict__ x, const _Float16* __restrict__ wxT,
    const float* __restrict__ bz, const float* __restrict__ br,
    const float* __restrict__ bh, _Float16* __restrict__ Xtmp) {
    __shared__ _Float16 Als[128][40];
    __shared__ _Float16 Bls[128][40];
    const int tid = threadIdx.x;
    const int n0 = blockIdx.x * 128;
    const int m0 = blockIdx.y * 128;
    const int lane = tid & 63;
    const int wave = tid >> 6;
    const int lm = lane & 15, lq = lane >> 4;
    const int wm = (wave >> 1) * 64, wn = (wave & 1) * 64;
    const int srow = tid >> 1;
    const int shalf = (tid & 1) * 16;

    floatx4 acc[4][4];
#pragma unroll
    for (int mi = 0; mi < 4; ++mi)
#pragma unroll
        for (int ni = 0; ni < 4; ++ni) acc[mi][ni] = (floatx4){0.f, 0.f, 0.f, 0.f};

    for (int k0 = 0; k0 < 1024; k0 += 32) {
        {
            const float* src = x + (size_t)(m0 + srow) * 1024 + k0 + shalf;
            float4 p0 = ((const float4*)src)[0];
            float4 p1 = ((const float4*)src)[1];
            float4 p2 = ((const float4*)src)[2];
            float4 p3 = ((const float4*)src)[3];
            half8 h0v = {(_Float16)p0.x, (_Float16)p0.y, (_Float16)p0.z, (_Float16)p0.w,
                         (_Float16)p1.x, (_Float16)p1.y, (_Float16)p1.z, (_Float16)p1.w};
            half8 h1v = {(_Float16)p2.x, (_Float16)p2.y, (_Float16)p2.z, (_Float16)p2.w,
                         (_Float16)p3.x, (_Float16)p3.y, (_Float16)p3.z, (_Float16)p3.w};
            *(half8*)&Als[srow][shalf] = h0v;
            *(half8*)&Als[srow][shalf + 8] = h1v;
            const _Float16* bsrc = wxT + (size_t)(n0 + srow) * 1024 + k0 + shalf;
            *(half8*)&Bls[srow][shalf] = ((const half8*)bsrc)[0];
            *(half8*)&Bls[srow][shalf + 8] = ((const half8*)bsrc)[1];
        }
        __syncthreads();
        half8 af[4], bf[4];
#pragma unroll
        for (int mi = 0; mi < 4; ++mi) af[mi] = *(const half8*)&Als[wm + mi * 16 + lm][lq * 8];
#pragma unroll
        for (int ni = 0; ni < 4; ++ni) bf[ni] = *(const half8*)&Bls[wn + ni * 16 + lm][lq * 8];
#pragma unroll
        for (int mi = 0; mi < 4; ++mi)
#pragma unroll
            for (int ni = 0; ni < 4; ++ni)
                acc[mi][ni] = __builtin_amdgcn_mfma_f32_16x16x32_f16(af[mi], bf[ni], acc[mi][ni], 0, 0, 0);
        __syncthreads();
    }
    // epilogue -> layout: idx = (((g*64+j)*3+mat)*512 + t)*256 + c*16 + b
#pragma unroll
    for (int mi = 0; mi < 4; ++mi) {
#pragma unroll
        for (int i = 0; i < 4; ++i) {
            int row = m0 + wm + mi * 16 + lq * 4 + i;  // (g*16+b)*512 + t
            int t = row & 511;
            int bglob = row >> 9;
            int g = bglob >> 4, b = bglob & 15;
#pragma unroll
            for (int ni = 0; ni < 4; ++ni) {
                int col = n0 + wn + ni * 16 + lm;  // mat*1024 + j*16 + c
                int mat = col >> 10;
                int jc = col - mat * 1024;
                int jj = jc >> 4, c = jc & 15;
                float bias = (mat == 0) ? bz[jc] : ((mat == 1) ? br[jc] : bh[jc]);
                size_t idx = ((((size_t)(g * 64 + jj) * 3 + mat) * 512 + t) << 8) + c * 16 + b;
                Xtmp[idx] = (_Float16)(acc[mi][ni][i] + bias);
            }
        }
    }
}

// ---------------------------------------------------------------------------
// 5) persistent sequential kernel — R5 structure exactly
//    counters: ch threshold 64t, cr 64(t+1), cn 64((t+1)>>2)
// ---------------------------------------------------------------------------
__global__ __launch_bounds__(256, 1) void gru_seq_kernel(
    const _Float16* __restrict__ Xtmp, const _Float16* __restrict__ wpack,
    const float* __restrict__ h0,
    _Float16* __restrict__ hfrag,   // [2][4][16384]
    _Float16* __restrict__ rfrag,   // [4][16384]
    _Float16* __restrict__ hnfrag,  // [4][16384]
    unsigned* flags_h, unsigned* flags_r, unsigned* flags_n,
    const float* __restrict__ bp, float* __restrict__ out) {
    const int wg = blockIdx.x;
    const int g = wg & 3;
    const int j = wg >> 2;
    const int tid = threadIdx.x;
    const int wave = tid >> 6;
    const int lane = tid & 63;
    const int lm = lane & 15;
    const int lq = lane >> 4;

    __shared__ __align__(16) _Float16 als[32 * 64 * 8];  // 32KB staged h A-frags
    __shared__ float zbuf[256];
    __shared__ float pbuf[256];
    __shared__ _Float16 rbuf[256];
    __shared__ _Float16 hbuf[256];
    __shared__ _Float16 nbuf[256];

    // persistent B-fragments: wave w holds matrix w (z,r,hc,Wp), 128 VGPR
    half8 W[32];
    {
        const half8* wp = (const half8*)wpack + (size_t)((j * 4 + wave) * 32) * 64 + lane;
#pragma unroll
        for (int kk = 0; kk < 32; ++kk) W[kk] = wp[kk * 64];
    }
    const float bpl = bp[j * 16 + lm];

    // one counter per (group, phase), 256B apart (separate cache lines)
    unsigned* ch = flags_h + g * 64;
    unsigned* cr = flags_r + g * 64;
    unsigned* cn = flags_n + g * 64;

    // transpose-store lane roles: one 8B chunk per lane covers the wg's
    // 16x16 output slice in A-frag order
    const int kkd = j >> 1;
    const int s_ = lane >> 5;
    const int b_ = (lane >> 1) & 15;
    const int hp_ = lane & 1;
    const size_t fidx = (size_t)((kkd * 64 + (2 * (j & 1) + s_) * 16 + b_) * 2 + hp_);
    const int ldsrd = b_ * 16 + s_ * 8 + hp_ * 4;  // halves offset in 16x16 buf

    // wave2 persistent h registers (own slice: b=lq*4+i, col=j*16+lm)
    float hreg[4];
    if (wave == 2) {
#pragma unroll
        for (int i = 0; i < 4; ++i)
            hreg[i] = h0[(size_t)(g * 16 + lq * 4 + i) * 1024 + j * 16 + lm];
    }

    unsigned long long* als8 = (unsigned long long*)als;

    for (int t = 0; t < T_STEPS; ++t) {
        const bool boundary = ((t & 3) == 3) && (t != T_STEPS - 1);

        // xv4 for waves 0/1: issue at step start, BEFORE the poll, so the
        // ~900ns HBM latency hides under poll+stage (R10 fix #1).
        half4v xv4b = {};
        if (wave < 2)
            xv4b = *(const half4v*)(Xtmp +
                ((((size_t)(g * 64 + j) * 3 + wave) * 512 + t) << 8) + lm * 16 + lq * 4);

        // ---- phase A: stage h(t) A-frags into LDS (waves 0,1) ----
        if (wave < 2) {
            poll_cnt(ch, 64u * (unsigned)t);
            const unsigned long long* hp8 =
                (const unsigned long long*)(hfrag + (size_t)((t & 1) * 4 + g) * 16384);
            unsigned long long tmp[32];
            const int base = wave * 16;
#pragma unroll
            for (int q = 0; q < 16; ++q) {
                int kk = base + q;
                tmp[2 * q] = AL(hp8 + (size_t)(kk * 64 + lane) * 2);
                tmp[2 * q + 1] = AL(hp8 + (size_t)(kk * 64 + lane) * 2 + 1);
            }
#pragma unroll
            for (int q = 0; q < 16; ++q) {
                int kk = base + q;
                als8[(kk * 64 + lane) * 2] = tmp[2 * q];
                als8[(kk * 64 + lane) * 2 + 1] = tmp[2 * q + 1];
            }
        }
        __syncthreads();  // S0: als valid

        // ---- phase B: z and r (waves 0,1), 2-acc ILP (R10 fix #2) ----
        if (wave < 2) {
            floatx4 a0 = {0.f, 0.f, 0.f, 0.f}, a1 = {0.f, 0.f, 0.f, 0.f};
#pragma unroll
            for (int kk = 0; kk < 32; kk += 2) {
                half8 av0 = *(const half8*)&als[(kk * 64 + lane) * 8];
                half8 av1 = *(const half8*)&als[((kk + 1) * 64 + lane) * 8];
                a0 = __builtin_amdgcn_mfma_f32_16x16x32_f16(av0, W[kk], a0, 0, 0, 0);
                a1 = __builtin_amdgcn_mfma_f32_16x16x32_f16(av1, W[kk + 1], a1, 0, 0, 0);
            }
            floatx4 acc = a0 + a1;
            if (wave == 0) {
#pragma unroll
                for (int i = 0; i < 4; ++i)
                    zbuf[lane * 4 + i] = 1.f / (1.f + __expf(-(acc[i] + (float)xv4b[i])));
            } else {
#pragma unroll
                for (int i = 0; i < 4; ++i)
                    rbuf[(lq * 4 + i) * 16 + lm] =
                        (_Float16)(1.f / (1.f + __expf(-(acc[i] + (float)xv4b[i]))));
                asm volatile("s_waitcnt lgkmcnt(0)" ::: "memory");
                unsigned long long rv8 = *(const unsigned long long*)&rbuf[ldsrd];
                AS((unsigned long long*)(rfrag + (size_t)g * 16384) + fidx, rv8);
                asm volatile("s_waitcnt vmcnt(0)" ::: "memory");  // release
                if (lane == 0) AADD(cr);
            }
        }
        __syncthreads();  // S1: zbuf valid

        // ---- phase C: candidate + blend (wave 2) / projection (wave 3) ----
        if (wave == 2) {
            half4v xv4 = *(const half4v*)(Xtmp +
                ((((size_t)(g * 64 + j) * 3 + 2) * 512 + t) << 8) + lm * 16 + lq * 4);
            poll_cnt(cr, 64u * (unsigned)(t + 1));
            const unsigned long long* rr8 = (const unsigned long long*)(rfrag + (size_t)g * 16384);
            // batch ALL r-fragment loads before the MFMA loop (one MALL latency)
            unsigned long long rtmp[64];
#pragma unroll
            for (int kk = 0; kk < 32; ++kk) {
                rtmp[2 * kk]     = AL(rr8 + (size_t)(kk * 64 + lane) * 2);
                rtmp[2 * kk + 1] = AL(rr8 + (size_t)(kk * 64 + lane) * 2 + 1);
            }
            floatx4 a0 = {0.f, 0.f, 0.f, 0.f}, a1 = {0.f, 0.f, 0.f, 0.f};
#pragma unroll
            for (int kk = 0; kk < 32; kk += 2) {
                half8 av0 = *(const half8*)&als[(kk * 64 + lane) * 8];
                half8 av1 = *(const half8*)&als[((kk + 1) * 64 + lane) * 8];
                U16 rc0, rc1;
                rc0.u[0] = rtmp[2 * kk];     rc0.u[1] = rtmp[2 * kk + 1];
                rc1.u[0] = rtmp[2 * kk + 2]; rc1.u[1] = rtmp[2 * kk + 3];
                a0 = __builtin_amdgcn_mfma_f32_16x16x32_f16(av0 * rc0.h, W[kk], a0, 0, 0, 0);
                a1 = __builtin_amdgcn_mfma_f32_16x16x32_f16(av1 * rc1.h, W[kk + 1], a1, 0, 0, 0);
            }
            floatx4 acc = a0 + a1;
            const bool post_b = (t > 0) && ((t & 3) == 0);
            float hn_[4];
#pragma unroll
            for (int i = 0; i < 4; ++i) {
                float hp = post_b ? pbuf[(lq * 4 + i) * 16 + lm] : hreg[i];
                float z = zbuf[lane * 4 + i];
                float hc = tanhf(acc[i] + (float)xv4[i]);
                float hn = (1.f - z) * hp + z * hc;
                hn_[i] = hn;
                hreg[i] = hn;
                hbuf[(lq * 4 + i) * 16 + lm] = (_Float16)hn;
            }
            asm volatile("s_waitcnt lgkmcnt(0)" ::: "memory");
            unsigned long long hv8 = *(const unsigned long long*)&hbuf[ldsrd];
            unsigned long long* dst8 = (unsigned long long*)(boundary
                ? (hnfrag + (size_t)g * 16384)
                : (hfrag + (size_t)(((t + 1) & 1) * 4 + g) * 16384));
            AS(dst8 + fidx, hv8);
            asm volatile("s_waitcnt vmcnt(0)" ::: "memory");  // release
            if (t < T_STEPS - 1 && lane == 0) {
                if (boundary) AADD(cn);
                else          AADD(ch);
            }
            // out[] stores AFTER the publish (off the release path)
#pragma unroll
            for (int i = 0; i < 4; ++i)
                __builtin_nontemporal_store(hn_[i],
                    &out[(size_t)((g * 16 + lq * 4 + i) * 512 + t) * 1024 + j * 16 + lm]);
        } else if (wave == 3 && boundary) {
            poll_cnt(cn, 64u * (unsigned)((t + 1) >> 2));
            const unsigned long long* nn8 = (const unsigned long long*)(hnfrag + (size_t)g * 16384);
            unsigned long long ntmp[64];
#pragma unroll
            for (int kk = 0; kk < 32; ++kk) {
                ntmp[2 * kk]     = AL(nn8 + (size_t)(kk * 64 + lane) * 2);
                ntmp[2 * kk + 1] = AL(nn8 + (size_t)(kk * 64 + lane) * 2 + 1);
            }
            floatx4 a0 = {0.f, 0.f, 0.f, 0.f}, a1 = {0.f, 0.f, 0.f, 0.f};
#pragma unroll
            for (int kk = 0; kk < 32; kk += 2) {
                U16 nc0, nc1;
                nc0.u[0] = ntmp[2 * kk];     nc0.u[1] = ntmp[2 * kk + 1];
                nc1.u[0] = ntmp[2 * kk + 2]; nc1.u[1] = ntmp[2 * kk + 3];
                a0 = __builtin_amdgcn_mfma_f32_16x16x32_f16(nc0.h, W[kk], a0, 0, 0, 0);
                a1 = __builtin_amdgcn_mfma_f32_16x16x32_f16(nc1.h, W[kk + 1], a1, 0, 0, 0);
            }
            floatx4 acc = a0 + a1;
#pragma unroll
            for (int i = 0; i < 4; ++i) {
                float hv = tanhf(acc[i] + bpl);
                pbuf[(lq * 4 + i) * 16 + lm] = hv;            // handoff to wave2 (t+1)
                nbuf[(lq * 4 + i) * 16 + lm] = (_Float16)hv;
            }
            asm volatile("s_waitcnt lgkmcnt(0)" ::: "memory");
            unsigned long long nv8 = *(const unsigned long long*)&nbuf[ldsrd];
            AS((unsigned long long*)(hfrag + (size_t)(((t + 1) & 1) * 4 + g) * 16384) + fidx, nv8);
            asm volatile("s_waitcnt vmcnt(0)" ::: "memory");  // release
            if (lane == 0) AADD(ch);
        }
    }
}

// ---------------------------------------------------------------------------
// host launcher
// ---------------------------------------------------------------------------
extern "C" void kernel_launch(void* const* d_in, const int* in_sizes, int n_in,
                              void* d_out, int out_size, void* d_ws, size_t ws_size,
                              hipStream_t stream) {
    (void)in_sizes; (void)n_in; (void)out_size; (void)ws_size;
    const float* x  = (const float*)d_in[0];
    const float* h0 = (const float*)d_in[1];
    const float* Wz = (const float*)d_in[2];
    const float* bz = (const float*)d_in[3];
    const float* Wr = (const float*)d_in[4];
    const float* br = (const float*)d_in[5];
    const float* Wh = (const float*)d_in[6];
    const float* bh = (const float*)d_in[7];
    const float* Wp = (const float*)d_in[8];
    const float* bp = (const float*)d_in[9];
    float* out = (float*)d_out;

    char* ws = (char*)d_ws;
    _Float16* wxT    = (_Float16*)(ws);                // 6,291,456 B
    _Float16* wpack  = (_Float16*)(ws + 6291456);      // 8,388,608 B
    _Float16* Xtmp   = (_Float16*)(ws + 14680064);     // 201,326,592 B
    _Float16* hfrag  = (_Float16*)(ws + 216006656);    // 262,144 B  [2][4][16384]
    _Float16* rfrag  = (_Float16*)(ws + 216268800);    // 131,072 B  [4][16384]
    _Float16* hnfrag = (_Float16*)(ws + 216399872);    // 131,072 B  [4][16384]
    unsigned* flags  = (unsigned*)(ws + 216530944);    // 3,072 B (counters)
    unsigned* flags_h = flags;
    unsigned* flags_r = flags + 256;
    unsigned* flags_n = flags + 512;

    pack_wxT<<<dim3(16, 16, 3), 256, 0, stream>>>(Wz, Wr, Wh, wxT);
    pack_wrec<<<2048, 256, 0, stream>>>(Wz, Wr, Wh, Wp, wpack);
    init_misc<<<32, 256, 0, stream>>>(h0, hfrag, flags);
    xproj_gemm<<<dim3(24, 256), 256, 0, stream>>>(x, wxT, bz, br, bh, Xtmp);
    gru_seq_kernel<<<256, 256, 0, stream>>>(Xtmp, wpack, h0, hfrag, rfrag, hnfrag,
                                            flags_h, flags_r, flags_n, bp, out);
}